// Round 4
// baseline (3483.962 us; speedup 1.0000x reference)
//
#include <hip/hip_runtime.h>
#include <stdint.h>

// AutoRegressiveLSTM: B=128, T=1024, I=128, H=1024, O=128. 4H=4096, K=I+H (+O fused)
#define Tn 1024
#define In 128

typedef __attribute__((ext_vector_type(8))) short short8;
typedef __attribute__((ext_vector_type(4))) float f32x4;
typedef unsigned long long u64;

// ---- workspace layout (bytes) ----
#define WS_WFRAG  0ull                         // 32u*8nt*40kt*64lane*16B = 10,485,760
#define WS_WOUT   (WS_WFRAG + 10485760ull)     // 8u*32kt*1024B = 262,144
#define WS_Z0     (WS_WOUT + 262144ull)        // 8m*4kt*1024B = 32,768
#define WS_HBUF   (WS_Z0 + 32768ull)           // 2buf*8m*32kt*1024B = 524,288
#define WS_BIAS   (WS_HBUF + 524288ull)        // 4096*4
#define WS_CNT    (WS_BIAS + 16384ull)         // 8m*1024t*4B flags (line-disjoint per group)
// total ~11.35 MB

__device__ __forceinline__ unsigned short f2bf(float f) {
  unsigned u = __builtin_bit_cast(unsigned, f);
  return (unsigned short)((u + 0x7FFFu + ((u >> 16) & 1u)) >> 16);  // RNE
}
__device__ __forceinline__ float fast_sig(float v) {
  float e = __builtin_amdgcn_exp2f(-1.44269504089f * v);
  return __builtin_amdgcn_rcpf(1.0f + e);
}
__device__ __forceinline__ float fast_tanh(float v) {
  float a = fabsf(v);
  float e = __builtin_amdgcn_exp2f(-2.88539008178f * a);
  float r = (1.0f - e) * __builtin_amdgcn_rcpf(1.0f + e);
  return copysignf(r, v);
}

// ---------------------------------------------------------------------------
// K1: fused weights -> bf16 B-fragments.
// ---------------------------------------------------------------------------
__global__ void k_wfrag(const float* __restrict__ Wih, const float* __restrict__ Whh,
                        const float* __restrict__ Wout, char* __restrict__ ws) {
  const int u = blockIdx.x, nt = blockIdx.y, kt = blockIdx.z;
  const int lane = threadIdx.x;
  const int col = lane & 15, quad = lane >> 4;
  const int r = nt * 16 + col;
  const int g = r >> 5, jj = r & 31;
  const int n = g * 1024 + u * 32 + jj;
  float v[8];
  if (kt < 32) {
    const int k = kt * 32 + quad * 8;
    #pragma unroll
    for (int e = 0; e < 8; e++) v[e] = Whh[(size_t)n * 1024 + k + e];
    const float* wo = Wih + (size_t)n * 256 + 128;
    for (int o = 0; o < 128; o++) {
      const float wv = wo[o];
      const float* wr = Wout + (size_t)o * 1024 + k;
      #pragma unroll
      for (int e = 0; e < 8; e++) v[e] = fmaf(wv, wr[e], v[e]);
    }
  } else if (kt < 36) {
    const int k = (kt - 32) * 32 + quad * 8;
    #pragma unroll
    for (int e = 0; e < 8; e++) v[e] = Wih[(size_t)n * 256 + k + e];
  } else {
    const int o = (kt - 36) * 32 + quad * 8;
    #pragma unroll
    for (int e = 0; e < 8; e++) v[e] = Wih[(size_t)n * 256 + 128 + o + e];
  }
  short8 pk;
  #pragma unroll
  for (int e = 0; e < 8; e++) pk[e] = (short)f2bf(v[e]);
  *(short8*)(ws + WS_WFRAG + ((size_t)((u * 8 + nt) * 40 + kt) * 64 + lane) * 16) = pk;
}

// ---------------------------------------------------------------------------
// K2: misc setup (woutfrag, hn->frag into hbuf[1], z0 frag, bias2, flag zero,
//     XCD-scratch zero at out[0..511])
// ---------------------------------------------------------------------------
__global__ void k_misc(const float* __restrict__ Wout, const float* __restrict__ hn,
                       const float* __restrict__ out_t, const float* __restrict__ bout,
                       const float* __restrict__ bih, const float* __restrict__ bhh,
                       const float* __restrict__ Wih, float* __restrict__ outp,
                       char* __restrict__ ws) {
  const int blk = blockIdx.x, lane = threadIdx.x;
  const int col = lane & 15, quad = lane >> 4;
  if (blk < 256) {                       // woutfrag[u][kt][lane][8] = Wout[o][j]
    const int u = blk >> 5, kt = blk & 31;
    const int o = u * 16 + col, j0 = kt * 32 + quad * 8;
    short8 pk;
    #pragma unroll
    for (int e = 0; e < 8; e++) pk[e] = (short)f2bf(Wout[(size_t)o * 1024 + j0 + e]);
    *(short8*)(ws + WS_WOUT + ((size_t)(u * 32 + kt) * 64 + lane) * 16) = pk;
  } else if (blk < 512) {                // hn -> A-frag layout into hbuf[1]
    const int t2 = blk - 256;
    const int mm = t2 >> 5, kt = t2 & 31;
    const int b = mm * 16 + col, j0 = kt * 32 + quad * 8;
    short8 pk;
    #pragma unroll
    for (int e = 0; e < 8; e++) pk[e] = (short)f2bf(hn[(size_t)b * 1024 + j0 + e]);
    *(short8*)(ws + WS_HBUF + ((size_t)((8 + mm) * 32 + kt) * 64 + lane) * 16) = pk;
  } else if (blk < 544) {                // z0 = output_t - b_out - hn@Wout^T (A-frag bf16)
    const int t2 = blk - 512;
    const int mm = t2 >> 2, kz = t2 & 3;
    const int b = mm * 16 + col;
    const int o0 = kz * 32 + quad * 8;
    float acc[8];
    #pragma unroll
    for (int e = 0; e < 8; e++) acc[e] = out_t[(size_t)b * 128 + o0 + e] - bout[o0 + e];
    for (int j = 0; j < 1024; j += 4) {
      const f32x4 h4 = *(const f32x4*)(hn + (size_t)b * 1024 + j);
      #pragma unroll
      for (int e = 0; e < 8; e++) {
        const f32x4 w4 = *(const f32x4*)(Wout + (size_t)(o0 + e) * 1024 + j);
        acc[e] -= h4[0] * w4[0] + h4[1] * w4[1] + h4[2] * w4[2] + h4[3] * w4[3];
      }
    }
    short8 pk;
    #pragma unroll
    for (int e = 0; e < 8; e++) pk[e] = (short)f2bf(acc[e]);
    *(short8*)(ws + WS_Z0 + ((size_t)(mm * 4 + kz) * 64 + lane) * 16) = pk;
  } else if (blk < 608) {                // bias2[n] = b_ih + b_hh + W_ihO @ b_out
    const int n = (blk - 544) * 64 + lane;
    float v = bih[n] + bhh[n];
    const float* wo = Wih + (size_t)n * 256 + 128;
    for (int o = 0; o < 128; o++) v = fmaf(wo[o], bout[o], v);
    ((float*)(ws + WS_BIAS))[n] = v;
  } else if (blk < 616) {                // zero flag counters (8192 ints)
    int* c = (int*)(ws + WS_CNT);
    const int base = ((blk - 608) * 64 + lane) * 16;
    #pragma unroll
    for (int k = 0; k < 16; k++) c[base + k] = 0;
  } else {                               // zero XCD-exchange scratch (out[0..511])
    int* c = (int*)outp;
    #pragma unroll
    for (int k = 0; k < 8; k++) c[lane * 8 + k] = 0;
  }
}

// ---------------------------------------------------------------------------
// Main persistent kernel: 256 WGs x 512 thr. Adaptive XCD grouping (round-2
// proven). Flags: round-0/2 proven system-scope (MALL) fetch_add + relaxed
// spin in BOTH modes. Fast path: only the bulk 32KB h exchange uses sc0
// (XCD-L2-local) stores/loads; producer's vmcnt(0) before the MALL flag
// guarantees L2 commit happens-before flag visibility. t=0 staging uses the
// MALL path (k_misc data; avoids cross-dispatch L2 staleness).
// Gates GEMM: 4-way K-split. Wave w = (kg=w>>1, half=w&1) covers 9 kt x 4
// row-tiles, so each A-frag ds_read feeds 4 MFMAs (72 A-reads/step instead of
// 288 -- LDS read pipe was the longest). Partials in pbuf[4][128][20], summed
// in the nonlinear phase (bias folded into kg==0; z0 kt 36+kg at t=0).
// ---------------------------------------------------------------------------
__launch_bounds__(512, 2)
__global__ void k_main(const float* __restrict__ x, const int* __restrict__ seq,
                       const float* __restrict__ cn, const float* __restrict__ b_out,
                       float* __restrict__ out, char* __restrict__ ws) {
  __shared__ short8 a_lds[40 * 64];        // A fragments: 32 h + 4 x + 4 z0 (40 KB)
  __shared__ float  pbuf[4 * 128 * 20];    // K-split partials [kg][row r][batch b] (40 KB)
  __shared__ short8 htile[64];             // new h tile (16b x 32j) in frag order
  __shared__ float  ysred[8 * 16 * 20];    // ys split-K partials [q][o][b]
  __shared__ float  bias_lds[128];
  __shared__ int    seq_lds[16];

  const int tid  = threadIdx.x;
  const int lane = tid & 63;
  const int w    = tid >> 6;               // wave id 0..7
  const int wg   = blockIdx.x;

  int* cnt = (int*)(ws + WS_CNT);

  // ---- one-time placement detection + adaptive group formation (round-2) ----
  int m_, u_, fast_;
  {
    int* ids = (int*)ysred;                // 260 ints << sizeof(ysred)
    int* scr = (int*)out;
    if (tid == 0) {
      int myxcd;
      asm volatile("s_getreg_b32 %0, hwreg(HW_REG_XCC_ID)" : "=s"(myxcd));
      myxcd &= 7;
      ids[259] = myxcd;
      __hip_atomic_store(&scr[8 + wg], myxcd, __ATOMIC_RELAXED, __HIP_MEMORY_SCOPE_SYSTEM);
      __hip_atomic_fetch_add(&scr[0], 1, __ATOMIC_ACQ_REL, __HIP_MEMORY_SCOPE_SYSTEM);
      while (__hip_atomic_load(&scr[0], __ATOMIC_ACQUIRE, __HIP_MEMORY_SCOPE_SYSTEM) < 256) {}
    }
    __syncthreads();
    if (tid < 256)
      ids[tid] = __hip_atomic_load(&scr[8 + tid], __ATOMIC_RELAXED,
                                   __HIP_MEMORY_SCOPE_SYSTEM) & 7;
    __syncthreads();
    if (tid == 0) {
      const int myxcd = ids[259];
      int cx[8] = {0, 0, 0, 0, 0, 0, 0, 0};
      int rank = 0;
      for (int i = 0; i < 256; i++) {
        const int xi = ids[i];
        cx[xi]++;
        if (xi == myxcd && i < wg) rank++;
      }
      bool bal = true;
      for (int k = 0; k < 8; k++) bal = bal && (cx[k] == 32);
      ids[256] = bal ? myxcd : (wg & 7);
      ids[257] = bal ? rank : (wg >> 3);
      ids[258] = bal ? 1 : 0;
      __hip_atomic_fetch_add(&scr[1], 1, __ATOMIC_ACQ_REL, __HIP_MEMORY_SCOPE_SYSTEM);
      while (__hip_atomic_load(&scr[1], __ATOMIC_ACQUIRE, __HIP_MEMORY_SCOPE_SYSTEM) < 256) {}
    }
    __syncthreads();
    m_ = ids[256]; u_ = ids[257]; fast_ = ids[258];
    __syncthreads();                       // release overlay before ysred reuse
  }
  const int  m     = m_;
  const int  u     = u_;
  const bool fastp = (fast_ != 0);

  const char* wfrag = ws + WS_WFRAG;
  const char* woutf = ws + WS_WOUT;
  char* hbuf  = ws + WS_HBUF;
  const float* bias2 = (const float*)(ws + WS_BIAS);

  // ---- K-split role: K-group kg (9 kts), row-tile half (4 tiles) ----
  const int kg   = w >> 1;                 // 0..3 -> kt in [kg*9, kg*9+9)
  const int half = w & 1;                  // row-tiles half*4 .. half*4+3
  const int col16 = lane & 15, bq4 = (lane >> 4) * 4;

  // persistent weight B-fragments: 36 + 4 z0 = 40 x 16B = 160 regs
  short8 bfr[36];
  short8 bz[4];
  {
    #pragma unroll
    for (int j = 0; j < 4; j++) {
      #pragma unroll
      for (int kk = 0; kk < 9; kk++)
        bfr[j * 9 + kk] = *(const short8*)(wfrag +
            ((size_t)((u * 8 + half * 4 + j) * 40 + kg * 9 + kk) * 64 + lane) * 16);
      bz[j] = *(const short8*)(wfrag +
          ((size_t)((u * 8 + half * 4 + j) * 40 + 36 + kg) * 64 + lane) * 16);
    }
  }
  if (tid < 16) seq_lds[tid] = seq[m * 16 + tid];
  if (tid < 128) {
    const int g = tid >> 5, jj = tid & 31;
    bias_lds[tid] = bias2[g * 1024 + u * 32 + jj];
  }
  const int b_loc  = tid & 15;   // batch within group
  const int jj_loc = tid >> 4;   // unit within WG (0..31)
  float c_reg = cn[(size_t)(m * 16 + b_loc) * 1024 + u * 32 + jj_loc];
  __syncthreads();

  #pragma unroll 1
  for (int tt = 0; tt <= Tn; tt++) {
    // ---- stage x_t (masked, bf16, frag layout) ----
    if (tt < Tn && tid < 256) {
      const int kt4 = tid >> 6, ln = tid & 63;
      const int b = ln & 15, quad = ln >> 4;
      const int i0 = kt4 * 32 + quad * 8;
      const float* xp = x + ((size_t)(m * 16 + b) * Tn + tt) * In + i0;
      const float mk = (tt < seq_lds[b]) ? 1.0f : 0.0f;
      const f32x4 x0 = *(const f32x4*)xp;
      const f32x4 x1 = *(const f32x4*)(xp + 4);
      short8 pk;
      pk[0] = (short)f2bf(x0[0] * mk); pk[1] = (short)f2bf(x0[1] * mk);
      pk[2] = (short)f2bf(x0[2] * mk); pk[3] = (short)f2bf(x0[3] * mk);
      pk[4] = (short)f2bf(x1[0] * mk); pk[5] = (short)f2bf(x1[1] * mk);
      pk[6] = (short)f2bf(x1[2] * mk); pk[7] = (short)f2bf(x1[3] * mk);
      a_lds[(32 + kt4) * 64 + ln] = pk;
    }
    // ---- stage z0 correction frags (t=0 only) ----
    if (tt == 0 && tid < 256) {
      const int kz = tid >> 6, ln = tid & 63;
      a_lds[(36 + kz) * 64 + ln] =
          *(const short8*)(ws + WS_Z0 + ((size_t)(m * 4 + kz) * 64 + ln) * 16);
    }
    // ---- wait for all 32 producers of h_{tt-1} (round-0/2 proven MALL spin) ----
    if (tt >= 1 && tid == 0) {
      while (__hip_atomic_load(&cnt[m * 1024 + (tt - 1)], __ATOMIC_RELAXED,
                               __HIP_MEMORY_SCOPE_SYSTEM) < 32) {}
    }
    __syncthreads();
    // ---- stage h_{tt-1} (32 KB) into LDS ----
    {
      const char* srcb = hbuf + (size_t)((((tt + 1) & 1) * 8) + m) * 32768;
      if (fastp && tt >= 1) {
        // XCD-L2-local loads: data written by same-L2 sc0 stores this dispatch.
        const f32x4* sp = (const f32x4*)srcb;
        f32x4 t0, t1, t2, t3;
        asm volatile(
            "global_load_dwordx4 %0, %4, off sc0\n\t"
            "global_load_dwordx4 %1, %5, off sc0\n\t"
            "global_load_dwordx4 %2, %6, off sc0\n\t"
            "global_load_dwordx4 %3, %7, off sc0\n\t"
            "s_waitcnt vmcnt(0)"
            : "=&v"(t0), "=&v"(t1), "=&v"(t2), "=&v"(t3)
            : "v"(sp + tid), "v"(sp + 512 + tid), "v"(sp + 1024 + tid),
              "v"(sp + 1536 + tid)
            : "memory");
        f32x4* dst = (f32x4*)a_lds;
        dst[tid] = t0; dst[512 + tid] = t1; dst[1024 + tid] = t2; dst[1536 + tid] = t3;
      } else {
        const u64* src = (const u64*)srcb;
        u64 tmp[8];
        #pragma unroll
        for (int s = 0; s < 8; s++)
          tmp[s] = __hip_atomic_load(&src[s * 512 + tid], __ATOMIC_RELAXED,
                                     __HIP_MEMORY_SCOPE_SYSTEM);
        u64* dst = (u64*)a_lds;
        #pragma unroll
        for (int s = 0; s < 8; s++) dst[s * 512 + tid] = tmp[s];
      }
    }
    __syncthreads();

    // ---- gates (4-way K-split) + state update ----
    if (tt < Tn) {
      f32x4 acc0, acc1, acc2, acc3;
      if (kg == 0) {
        const float b0 = bias_lds[(half * 4 + 0) * 16 + col16];
        const float b1 = bias_lds[(half * 4 + 1) * 16 + col16];
        const float b2 = bias_lds[(half * 4 + 2) * 16 + col16];
        const float b3 = bias_lds[(half * 4 + 3) * 16 + col16];
        acc0 = {b0, b0, b0, b0}; acc1 = {b1, b1, b1, b1};
        acc2 = {b2, b2, b2, b2}; acc3 = {b3, b3, b3, b3};
      } else {
        acc0 = {0.f, 0.f, 0.f, 0.f}; acc1 = {0.f, 0.f, 0.f, 0.f};
        acc2 = {0.f, 0.f, 0.f, 0.f}; acc3 = {0.f, 0.f, 0.f, 0.f};
      }
      #pragma unroll
      for (int kk = 0; kk < 9; kk++) {       // one A-read feeds 4 MFMAs
        const short8 a = a_lds[(kg * 9 + kk) * 64 + lane];
        acc0 = __builtin_amdgcn_mfma_f32_16x16x32_bf16(a, bfr[0 * 9 + kk], acc0, 0, 0, 0);
        acc1 = __builtin_amdgcn_mfma_f32_16x16x32_bf16(a, bfr[1 * 9 + kk], acc1, 0, 0, 0);
        acc2 = __builtin_amdgcn_mfma_f32_16x16x32_bf16(a, bfr[2 * 9 + kk], acc2, 0, 0, 0);
        acc3 = __builtin_amdgcn_mfma_f32_16x16x32_bf16(a, bfr[3 * 9 + kk], acc3, 0, 0, 0);
      }
      if (tt == 0) {                          // step-0 out_t correction (z-kt 36+kg)
        const short8 a = a_lds[(36 + kg) * 64 + lane];
        acc0 = __builtin_amdgcn_mfma_f32_16x16x32_bf16(a, bz[0], acc0, 0, 0, 0);
        acc1 = __builtin_amdgcn_mfma_f32_16x16x32_bf16(a, bz[1], acc1, 0, 0, 0);
        acc2 = __builtin_amdgcn_mfma_f32_16x16x32_bf16(a, bz[2], acc2, 0, 0, 0);
        acc3 = __builtin_amdgcn_mfma_f32_16x16x32_bf16(a, bz[3], acc3, 0, 0, 0);
      }
      {
        const int rb = kg * 128 + (half * 4) * 16 + col16;
        *(f32x4*)&pbuf[(size_t)(rb +  0) * 20 + bq4] = acc0;
        *(f32x4*)&pbuf[(size_t)(rb + 16) * 20 + bq4] = acc1;
        *(f32x4*)&pbuf[(size_t)(rb + 32) * 20 + bq4] = acc2;
        *(f32x4*)&pbuf[(size_t)(rb + 48) * 20 + bq4] = acc3;
      }
      __syncthreads();
      {
        const int r0 = 0 * 32 + jj_loc, r1 = 1 * 32 + jj_loc;
        const int r2 = 2 * 32 + jj_loc, r3 = 3 * 32 + jj_loc;
        const float Gi = pbuf[(0 * 128 + r0) * 20 + b_loc] + pbuf[(1 * 128 + r0) * 20 + b_loc]
                       + pbuf[(2 * 128 + r0) * 20 + b_loc] + pbuf[(3 * 128 + r0) * 20 + b_loc];
        const float Gf = pbuf[(0 * 128 + r1) * 20 + b_loc] + pbuf[(1 * 128 + r1) * 20 + b_loc]
                       + pbuf[(2 * 128 + r1) * 20 + b_loc] + pbuf[(3 * 128 + r1) * 20 + b_loc];
        const float Gg = pbuf[(0 * 128 + r2) * 20 + b_loc] + pbuf[(1 * 128 + r2) * 20 + b_loc]
                       + pbuf[(2 * 128 + r2) * 20 + b_loc] + pbuf[(3 * 128 + r2) * 20 + b_loc];
        const float Go = pbuf[(0 * 128 + r3) * 20 + b_loc] + pbuf[(1 * 128 + r3) * 20 + b_loc]
                       + pbuf[(2 * 128 + r3) * 20 + b_loc] + pbuf[(3 * 128 + r3) * 20 + b_loc];
        const float ig = fast_sig(Gi), fg = fast_sig(Gf);
        const float gg = fast_tanh(Gg), og = fast_sig(Go);
        c_reg = fg * c_reg + ig * gg;
        const float h = og * fast_tanh(c_reg);
        ((short*)htile)[(b_loc + 16 * (jj_loc >> 3)) * 8 + (jj_loc & 7)] = (short)f2bf(h);
      }
      __syncthreads();
      if (tid < 64) {                          // wave0 publishes h tile + flag (ASAP)
        const short8 v = htile[lane];
        char* dstb = hbuf + (size_t)((tt & 1) * 8 + m) * 32768 + (size_t)u * 1024 +
                     (size_t)lane * 16;
        if (fastp) {
          // XCD-L2-local store; committed at L2 before the MALL flag below.
          asm volatile("global_store_dwordx4 %0, %1, off sc0" :: "v"(dstb), "v"(v)
                       : "memory");
        } else {
          u64* dstp = (u64*)dstb;
          const u64* pv = (const u64*)&v;
          __hip_atomic_store(&dstp[0], pv[0], __ATOMIC_RELAXED, __HIP_MEMORY_SCOPE_SYSTEM);
          __hip_atomic_store(&dstp[1], pv[1], __ATOMIC_RELAXED, __HIP_MEMORY_SCOPE_SYSTEM);
        }
        asm volatile("s_waitcnt vmcnt(0)" ::: "memory");   // h committed (L2 or MALL)
        if (tid == 0)
          __hip_atomic_fetch_add(&cnt[m * 1024 + tt], 1, __ATOMIC_RELAXED,
                                 __HIP_MEMORY_SCOPE_SYSTEM);
      }
    }

    // ---- ys[tt-1] = (h_{tt-1} @ Wout^T + b_out) * mask -- off critical path ----
    if (u < 8 && tt >= 1) {
      f32x4 yacc = {0.f, 0.f, 0.f, 0.f};
      const char* wob = woutf + ((size_t)(u * 32 + w * 4) * 64 + lane) * 16;
      #pragma unroll
      for (int i = 0; i < 4; i++) {
        const short8 bf = *(const short8*)(wob + (size_t)i * 1024);
        const short8 af = a_lds[(w * 4 + i) * 64 + lane];
        yacc = __builtin_amdgcn_mfma_f32_16x16x32_bf16(af, bf, yacc, 0, 0, 0);
      }
      {
        const int o = lane & 15, bq = (lane >> 4) * 4;
        *(f32x4*)&ysred[(w * 16 + o) * 20 + bq] = yacc;
      }
      __syncthreads();
      if (tid < 256) {
        const int o = tid & 15, b = tid >> 4;
        float s = 0.f;
        #pragma unroll
        for (int q = 0; q < 8; q++) s += ysred[(q * 16 + o) * 20 + b];
        s += b_out[u * 16 + o];
        const float val = ((tt - 1) < seq_lds[b]) ? s : 0.0f;
        out[((size_t)(m * 16 + b) * Tn + (tt - 1)) * 128 + u * 16 + o] = val;
      }
      __syncthreads();
    }
  }
}

extern "C" void kernel_launch(void* const* d_in, const int* in_sizes, int n_in,
                              void* d_out, int out_size, void* d_ws, size_t ws_size,
                              hipStream_t stream) {
  (void)in_sizes; (void)n_in; (void)out_size; (void)ws_size;
  const float* x    = (const float*)d_in[0];
  const int*   seq  = (const int*)d_in[1];
  const float* hn   = (const float*)d_in[2];
  const float* cn   = (const float*)d_in[3];
  const float* outt = (const float*)d_in[4];
  const float* Wih  = (const float*)d_in[5];
  const float* Whh  = (const float*)d_in[6];
  const float* bih  = (const float*)d_in[7];
  const float* bhh  = (const float*)d_in[8];
  const float* Wout = (const float*)d_in[9];
  const float* bout = (const float*)d_in[10];
  float* out = (float*)d_out;
  char* ws = (char*)d_ws;

  hipLaunchKernelGGL(k_wfrag, dim3(32, 8, 40), dim3(64), 0, stream, Wih, Whh, Wout, ws);
  hipLaunchKernelGGL(k_misc, dim3(617), dim3(64), 0, stream, Wout, hn, outt, bout,
                     bih, bhh, Wih, out, ws);
  void* args[] = {(void*)&x, (void*)&seq, (void*)&cn, (void*)&bout, (void*)&out, (void*)&ws};
  hipLaunchCooperativeKernel((const void*)k_main, dim3(256), dim3(512), args, 0, stream);
}

// Round 5
// 3215.620 us; speedup vs baseline: 1.0834x; 1.0834x over previous
//
#include <hip/hip_runtime.h>
#include <stdint.h>

// AutoRegressiveLSTM: B=128, T=1024, I=128, H=1024, O=128. 4H=4096, K=I+H (+O fused)
#define Tn 1024
#define In 128

typedef __attribute__((ext_vector_type(8))) short short8;
typedef __attribute__((ext_vector_type(4))) float f32x4;
typedef unsigned long long u64;

// ---- workspace layout (bytes) ----
#define WS_WFRAG  0ull                         // 32u*8nt*40kt*64lane*16B = 10,485,760
#define WS_WOUT   (WS_WFRAG + 10485760ull)     // 8u*32kt*1024B = 262,144
#define WS_Z0     (WS_WOUT + 262144ull)        // 8m*4kt*1024B = 32,768
#define WS_HBUF   (WS_Z0 + 32768ull)           // 2buf*8m*32kt*1024B = 524,288
#define WS_BIAS   (WS_HBUF + 524288ull)        // 4096*4
#define WS_CNT    (WS_BIAS + 16384ull)         // 8m*1024t*4B flags (line-disjoint per group)
// total ~11.35 MB

__device__ __forceinline__ unsigned short f2bf(float f) {
  unsigned u = __builtin_bit_cast(unsigned, f);
  return (unsigned short)((u + 0x7FFFu + ((u >> 16) & 1u)) >> 16);  // RNE
}
__device__ __forceinline__ float fast_sig(float v) {
  float e = __builtin_amdgcn_exp2f(-1.44269504089f * v);
  return __builtin_amdgcn_rcpf(1.0f + e);
}
__device__ __forceinline__ float fast_tanh(float v) {
  float a = fabsf(v);
  float e = __builtin_amdgcn_exp2f(-2.88539008178f * a);
  float r = (1.0f - e) * __builtin_amdgcn_rcpf(1.0f + e);
  return copysignf(r, v);
}

// ---------------------------------------------------------------------------
// K1: fused weights -> bf16 B-fragments.
// ---------------------------------------------------------------------------
__global__ void k_wfrag(const float* __restrict__ Wih, const float* __restrict__ Whh,
                        const float* __restrict__ Wout, char* __restrict__ ws) {
  const int u = blockIdx.x, nt = blockIdx.y, kt = blockIdx.z;
  const int lane = threadIdx.x;
  const int col = lane & 15, quad = lane >> 4;
  const int r = nt * 16 + col;
  const int g = r >> 5, jj = r & 31;
  const int n = g * 1024 + u * 32 + jj;
  float v[8];
  if (kt < 32) {
    const int k = kt * 32 + quad * 8;
    #pragma unroll
    for (int e = 0; e < 8; e++) v[e] = Whh[(size_t)n * 1024 + k + e];
    const float* wo = Wih + (size_t)n * 256 + 128;
    for (int o = 0; o < 128; o++) {
      const float wv = wo[o];
      const float* wr = Wout + (size_t)o * 1024 + k;
      #pragma unroll
      for (int e = 0; e < 8; e++) v[e] = fmaf(wv, wr[e], v[e]);
    }
  } else if (kt < 36) {
    const int k = (kt - 32) * 32 + quad * 8;
    #pragma unroll
    for (int e = 0; e < 8; e++) v[e] = Wih[(size_t)n * 256 + k + e];
  } else {
    const int o = (kt - 36) * 32 + quad * 8;
    #pragma unroll
    for (int e = 0; e < 8; e++) v[e] = Wih[(size_t)n * 256 + 128 + o + e];
  }
  short8 pk;
  #pragma unroll
  for (int e = 0; e < 8; e++) pk[e] = (short)f2bf(v[e]);
  *(short8*)(ws + WS_WFRAG + ((size_t)((u * 8 + nt) * 40 + kt) * 64 + lane) * 16) = pk;
}

// ---------------------------------------------------------------------------
// K2: misc setup (woutfrag, hn->frag into hbuf[1], z0 frag, bias2, flag zero,
//     XCD-scratch zero at out[0..511])
// ---------------------------------------------------------------------------
__global__ void k_misc(const float* __restrict__ Wout, const float* __restrict__ hn,
                       const float* __restrict__ out_t, const float* __restrict__ bout,
                       const float* __restrict__ bih, const float* __restrict__ bhh,
                       const float* __restrict__ Wih, float* __restrict__ outp,
                       char* __restrict__ ws) {
  const int blk = blockIdx.x, lane = threadIdx.x;
  const int col = lane & 15, quad = lane >> 4;
  if (blk < 256) {                       // woutfrag[u][kt][lane][8] = Wout[o][j]
    const int u = blk >> 5, kt = blk & 31;
    const int o = u * 16 + col, j0 = kt * 32 + quad * 8;
    short8 pk;
    #pragma unroll
    for (int e = 0; e < 8; e++) pk[e] = (short)f2bf(Wout[(size_t)o * 1024 + j0 + e]);
    *(short8*)(ws + WS_WOUT + ((size_t)(u * 32 + kt) * 64 + lane) * 16) = pk;
  } else if (blk < 512) {                // hn -> A-frag layout into hbuf[1]
    const int t2 = blk - 256;
    const int mm = t2 >> 5, kt = t2 & 31;
    const int b = mm * 16 + col, j0 = kt * 32 + quad * 8;
    short8 pk;
    #pragma unroll
    for (int e = 0; e < 8; e++) pk[e] = (short)f2bf(hn[(size_t)b * 1024 + j0 + e]);
    *(short8*)(ws + WS_HBUF + ((size_t)((8 + mm) * 32 + kt) * 64 + lane) * 16) = pk;
  } else if (blk < 544) {                // z0 = output_t - b_out - hn@Wout^T (A-frag bf16)
    const int t2 = blk - 512;
    const int mm = t2 >> 2, kz = t2 & 3;
    const int b = mm * 16 + col;
    const int o0 = kz * 32 + quad * 8;
    float acc[8];
    #pragma unroll
    for (int e = 0; e < 8; e++) acc[e] = out_t[(size_t)b * 128 + o0 + e] - bout[o0 + e];
    for (int j = 0; j < 1024; j += 4) {
      const f32x4 h4 = *(const f32x4*)(hn + (size_t)b * 1024 + j);
      #pragma unroll
      for (int e = 0; e < 8; e++) {
        const f32x4 w4 = *(const f32x4*)(Wout + (size_t)(o0 + e) * 1024 + j);
        acc[e] -= h4[0] * w4[0] + h4[1] * w4[1] + h4[2] * w4[2] + h4[3] * w4[3];
      }
    }
    short8 pk;
    #pragma unroll
    for (int e = 0; e < 8; e++) pk[e] = (short)f2bf(acc[e]);
    *(short8*)(ws + WS_Z0 + ((size_t)(mm * 4 + kz) * 64 + lane) * 16) = pk;
  } else if (blk < 608) {                // bias2[n] = b_ih + b_hh + W_ihO @ b_out
    const int n = (blk - 544) * 64 + lane;
    float v = bih[n] + bhh[n];
    const float* wo = Wih + (size_t)n * 256 + 128;
    for (int o = 0; o < 128; o++) v = fmaf(wo[o], bout[o], v);
    ((float*)(ws + WS_BIAS))[n] = v;
  } else if (blk < 616) {                // zero flag counters (8192 ints)
    int* c = (int*)(ws + WS_CNT);
    const int base = ((blk - 608) * 64 + lane) * 16;
    #pragma unroll
    for (int k = 0; k < 16; k++) c[base + k] = 0;
  } else {                               // zero XCD-exchange scratch (out[0..511])
    int* c = (int*)outp;
    #pragma unroll
    for (int k = 0; k < 8; k++) c[lane * 8 + k] = 0;
  }
}

// ---------------------------------------------------------------------------
// Main persistent kernel: 256 WGs x 512 thr. Round-2 proven structure:
// adaptive XCD grouping; MALL fetch_add/spin flags; sc0 L2-local 32KB h
// exchange on the fast path; round-2 gates GEMM (per-wave row-tile, 2 MFMA
// chains). Round-5 deltas ONLY:
//  (a) final ys __syncthreads removed -- it forced an s_waitcnt vmcnt(0)
//      drain of the `out` HBM store onto the 8 ys-WGs' critical path every
//      step (the compiler drains all vmem before s_barrier). The values it
//      protected (ysred, a_lds h-frags) are re-protected by barriers 1-5 of
//      the next iteration before any conflicting write.
//  (b) b_out[u*16+o] hoisted to LDS (was a per-step L2 load on the reduce
//      path before the out store).
// ---------------------------------------------------------------------------
__launch_bounds__(512, 2)
__global__ void k_main(const float* __restrict__ x, const int* __restrict__ seq,
                       const float* __restrict__ cn, const float* __restrict__ b_out,
                       float* __restrict__ out, char* __restrict__ ws) {
  __shared__ short8 a_lds[40 * 64];        // A fragments: 32 h + 4 x + 4 z0 (40 KB)
  __shared__ float  gates_lds[128 * 20];   // [row r][batch b], stride 20 (aligned+pad)
  __shared__ short8 htile[64];             // new h tile (16b x 32j) in frag order
  __shared__ float  ysred[8 * 16 * 20];    // ys split-K partials [q][o][b]
  __shared__ float  bias_lds[128];
  __shared__ float  bo_lds[16];            // b_out slice for this WG's o-tile
  __shared__ int    seq_lds[16];

  const int tid  = threadIdx.x;
  const int lane = tid & 63;
  const int w    = tid >> 6;               // wave id 0..7 (= gate N-tile)
  const int wg   = blockIdx.x;

  int* cnt = (int*)(ws + WS_CNT);

  // ---- one-time placement detection + adaptive group formation (round-2) ----
  int m_, u_, fast_;
  {
    int* ids = (int*)ysred;                // 260 ints << sizeof(ysred)
    int* scr = (int*)out;
    if (tid == 0) {
      int myxcd;
      asm volatile("s_getreg_b32 %0, hwreg(HW_REG_XCC_ID)" : "=s"(myxcd));
      myxcd &= 7;
      ids[259] = myxcd;
      __hip_atomic_store(&scr[8 + wg], myxcd, __ATOMIC_RELAXED, __HIP_MEMORY_SCOPE_SYSTEM);
      __hip_atomic_fetch_add(&scr[0], 1, __ATOMIC_ACQ_REL, __HIP_MEMORY_SCOPE_SYSTEM);
      while (__hip_atomic_load(&scr[0], __ATOMIC_ACQUIRE, __HIP_MEMORY_SCOPE_SYSTEM) < 256) {}
    }
    __syncthreads();
    if (tid < 256)
      ids[tid] = __hip_atomic_load(&scr[8 + tid], __ATOMIC_RELAXED,
                                   __HIP_MEMORY_SCOPE_SYSTEM) & 7;
    __syncthreads();
    if (tid == 0) {
      const int myxcd = ids[259];
      int cx[8] = {0, 0, 0, 0, 0, 0, 0, 0};
      int rank = 0;
      for (int i = 0; i < 256; i++) {
        const int xi = ids[i];
        cx[xi]++;
        if (xi == myxcd && i < wg) rank++;
      }
      bool bal = true;
      for (int k = 0; k < 8; k++) bal = bal && (cx[k] == 32);
      ids[256] = bal ? myxcd : (wg & 7);
      ids[257] = bal ? rank : (wg >> 3);
      ids[258] = bal ? 1 : 0;
      __hip_atomic_fetch_add(&scr[1], 1, __ATOMIC_ACQ_REL, __HIP_MEMORY_SCOPE_SYSTEM);
      while (__hip_atomic_load(&scr[1], __ATOMIC_ACQUIRE, __HIP_MEMORY_SCOPE_SYSTEM) < 256) {}
    }
    __syncthreads();
    m_ = ids[256]; u_ = ids[257]; fast_ = ids[258];
    __syncthreads();                       // release overlay before ysred reuse
  }
  const int  m     = m_;
  const int  u     = u_;
  const bool fastp = (fast_ != 0);

  const char* wfrag = ws + WS_WFRAG;
  const char* woutf = ws + WS_WOUT;
  char* hbuf  = ws + WS_HBUF;
  const float* bias2 = (const float*)(ws + WS_BIAS);

  // persistent weight B-fragments in VGPRs/AGPRs: 40 x 16B = 160 regs
  short8 bfr[40];
  {
    const char* base = wfrag + ((size_t)(u * 8 + w) * 40 * 64) * 16 + (size_t)lane * 16;
    #pragma unroll
    for (int kt = 0; kt < 40; kt++) bfr[kt] = *(const short8*)(base + (size_t)kt * 1024);
  }
  if (tid < 16) seq_lds[tid] = seq[m * 16 + tid];
  if (tid < 16 && u < 8) bo_lds[tid] = b_out[u * 16 + tid];
  if (tid < 128) {
    const int g = tid >> 5, jj = tid & 31;
    bias_lds[tid] = bias2[g * 1024 + u * 32 + jj];
  }
  const int b_loc  = tid & 15;   // batch within group
  const int jj_loc = tid >> 4;   // unit within WG (0..31)
  float c_reg = cn[(size_t)(m * 16 + b_loc) * 1024 + u * 32 + jj_loc];
  __syncthreads();

  #pragma unroll 1
  for (int tt = 0; tt <= Tn; tt++) {
    // ---- stage x_t (masked, bf16, frag layout) -- no h dependency, overlaps spin ----
    if (tt < Tn && tid < 256) {
      const int kt4 = tid >> 6, ln = tid & 63;
      const int b = ln & 15, quad = ln >> 4;
      const int i0 = kt4 * 32 + quad * 8;
      const float* xp = x + ((size_t)(m * 16 + b) * Tn + tt) * In + i0;
      const float mk = (tt < seq_lds[b]) ? 1.0f : 0.0f;
      const f32x4 x0 = *(const f32x4*)xp;
      const f32x4 x1 = *(const f32x4*)(xp + 4);
      short8 pk;
      pk[0] = (short)f2bf(x0[0] * mk); pk[1] = (short)f2bf(x0[1] * mk);
      pk[2] = (short)f2bf(x0[2] * mk); pk[3] = (short)f2bf(x0[3] * mk);
      pk[4] = (short)f2bf(x1[0] * mk); pk[5] = (short)f2bf(x1[1] * mk);
      pk[6] = (short)f2bf(x1[2] * mk); pk[7] = (short)f2bf(x1[3] * mk);
      a_lds[(32 + kt4) * 64 + ln] = pk;
    }
    // ---- stage z0 correction frags (t=0 only) ----
    if (tt == 0 && tid < 256) {
      const int kz = tid >> 6, ln = tid & 63;
      a_lds[(36 + kz) * 64 + ln] =
          *(const short8*)(ws + WS_Z0 + ((size_t)(m * 4 + kz) * 64 + ln) * 16);
    }
    // ---- wait for all 32 producers of h_{tt-1} (round-0/2 proven MALL spin) ----
    if (tt >= 1 && tid == 0) {
      while (__hip_atomic_load(&cnt[m * 1024 + (tt - 1)], __ATOMIC_RELAXED,
                               __HIP_MEMORY_SCOPE_SYSTEM) < 32) {}
    }
    __syncthreads();
    // ---- stage h_{tt-1} (32 KB) into LDS ----
    {
      const char* srcb = hbuf + (size_t)((((tt + 1) & 1) * 8) + m) * 32768;
      if (fastp && tt >= 1) {
        // XCD-L2-local loads: data written by same-L2 sc0 stores this dispatch.
        const f32x4* sp = (const f32x4*)srcb;
        f32x4 t0, t1, t2, t3;
        asm volatile(
            "global_load_dwordx4 %0, %4, off sc0\n\t"
            "global_load_dwordx4 %1, %5, off sc0\n\t"
            "global_load_dwordx4 %2, %6, off sc0\n\t"
            "global_load_dwordx4 %3, %7, off sc0\n\t"
            "s_waitcnt vmcnt(0)"
            : "=&v"(t0), "=&v"(t1), "=&v"(t2), "=&v"(t3)
            : "v"(sp + tid), "v"(sp + 512 + tid), "v"(sp + 1024 + tid),
              "v"(sp + 1536 + tid)
            : "memory");
        f32x4* dst = (f32x4*)a_lds;
        dst[tid] = t0; dst[512 + tid] = t1; dst[1024 + tid] = t2; dst[1536 + tid] = t3;
      } else {
        const u64* src = (const u64*)srcb;
        u64 tmp[8];
        #pragma unroll
        for (int s = 0; s < 8; s++)
          tmp[s] = __hip_atomic_load(&src[s * 512 + tid], __ATOMIC_RELAXED,
                                     __HIP_MEMORY_SCOPE_SYSTEM);
        u64* dst = (u64*)a_lds;
        #pragma unroll
        for (int s = 0; s < 8; s++) dst[s * 512 + tid] = tmp[s];
      }
    }
    __syncthreads();

    // ---- gates + state update (round-2 proven form) ----
    if (tt < Tn) {
      const float bias_v = bias_lds[w * 16 + (lane & 15)];
      f32x4 acc0 = {bias_v, bias_v, bias_v, bias_v};
      f32x4 acc1 = {0.f, 0.f, 0.f, 0.f};
      #pragma unroll
      for (int kt = 0; kt < 36; kt += 2) {     // two chains for MFMA latency
        const short8 a0 = a_lds[kt * 64 + lane];
        const short8 a1 = a_lds[(kt + 1) * 64 + lane];
        acc0 = __builtin_amdgcn_mfma_f32_16x16x32_bf16(a0, bfr[kt], acc0, 0, 0, 0);
        acc1 = __builtin_amdgcn_mfma_f32_16x16x32_bf16(a1, bfr[kt + 1], acc1, 0, 0, 0);
      }
      if (tt == 0) {                           // step-0 out_t correction
        #pragma unroll
        for (int kt = 36; kt < 40; kt += 2) {
          const short8 a0 = a_lds[kt * 64 + lane];
          const short8 a1 = a_lds[(kt + 1) * 64 + lane];
          acc0 = __builtin_amdgcn_mfma_f32_16x16x32_bf16(a0, bfr[kt], acc0, 0, 0, 0);
          acc1 = __builtin_amdgcn_mfma_f32_16x16x32_bf16(a1, bfr[kt + 1], acc1, 0, 0, 0);
        }
      }
      {
        const int r = w * 16 + (lane & 15);
        const int bq = (lane >> 4) * 4;
        f32x4 s;
        s[0] = acc0[0] + acc1[0]; s[1] = acc0[1] + acc1[1];
        s[2] = acc0[2] + acc1[2]; s[3] = acc0[3] + acc1[3];
        *(f32x4*)&gates_lds[r * 20 + bq] = s;
      }
      __syncthreads();
      {
        const float Gi = gates_lds[(0 * 32 + jj_loc) * 20 + b_loc];
        const float Gf = gates_lds[(1 * 32 + jj_loc) * 20 + b_loc];
        const float Gg = gates_lds[(2 * 32 + jj_loc) * 20 + b_loc];
        const float Go = gates_lds[(3 * 32 + jj_loc) * 20 + b_loc];
        const float ig = fast_sig(Gi), fg = fast_sig(Gf);
        const float gg = fast_tanh(Gg), og = fast_sig(Go);
        c_reg = fg * c_reg + ig * gg;
        const float h = og * fast_tanh(c_reg);
        ((short*)htile)[(b_loc + 16 * (jj_loc >> 3)) * 8 + (jj_loc & 7)] = (short)f2bf(h);
      }
      __syncthreads();
      if (tid < 64) {                          // wave0 publishes h tile + flag (ASAP)
        const short8 v = htile[lane];
        char* dstb = hbuf + (size_t)((tt & 1) * 8 + m) * 32768 + (size_t)u * 1024 +
                     (size_t)lane * 16;
        if (fastp) {
          // XCD-L2-local store; committed at L2 before the MALL flag below.
          asm volatile("global_store_dwordx4 %0, %1, off sc0" :: "v"(dstb), "v"(v)
                       : "memory");
        } else {
          u64* dstp = (u64*)dstb;
          const u64* pv = (const u64*)&v;
          __hip_atomic_store(&dstp[0], pv[0], __ATOMIC_RELAXED, __HIP_MEMORY_SCOPE_SYSTEM);
          __hip_atomic_store(&dstp[1], pv[1], __ATOMIC_RELAXED, __HIP_MEMORY_SCOPE_SYSTEM);
        }
        asm volatile("s_waitcnt vmcnt(0)" ::: "memory");   // h committed (L2 or MALL)
        if (tid == 0)
          __hip_atomic_fetch_add(&cnt[m * 1024 + tt], 1, __ATOMIC_RELAXED,
                                 __HIP_MEMORY_SCOPE_SYSTEM);
      }
    }

    // ---- ys[tt-1] = (h_{tt-1} @ Wout^T + b_out) * mask -- off critical path ----
    if (u < 8 && tt >= 1) {
      f32x4 yacc = {0.f, 0.f, 0.f, 0.f};
      const char* wob = woutf + ((size_t)(u * 32 + w * 4) * 64 + lane) * 16;
      #pragma unroll
      for (int i = 0; i < 4; i++) {
        const short8 bf = *(const short8*)(wob + (size_t)i * 1024);
        const short8 af = a_lds[(w * 4 + i) * 64 + lane];
        yacc = __builtin_amdgcn_mfma_f32_16x16x32_bf16(af, bf, yacc, 0, 0, 0);
      }
      {
        const int o = lane & 15, bq = (lane >> 4) * 4;
        *(f32x4*)&ysred[(w * 16 + o) * 20 + bq] = yacc;
      }
      __syncthreads();
      if (tid < 256) {
        const int o = tid & 15, b = tid >> 4;
        float s = 0.f;
        #pragma unroll
        for (int q = 0; q < 8; q++) s += ysred[(q * 16 + o) * 20 + b];
        s += bo_lds[o];
        const float val = ((tt - 1) < seq_lds[b]) ? s : 0.0f;
        out[((size_t)(m * 16 + b) * Tn + (tt - 1)) * 128 + u * 16 + o] = val;
      }
      // NOTE: no trailing __syncthreads here (round-5 delta). ysred/a_lds are
      // re-protected by barriers 1-5 of the next iteration before reuse; the
      // out-store vmcnt drain migrates to the post-spin barrier where it is
      // free instead of serializing an HBM RT into this step.
    }
  }
}

extern "C" void kernel_launch(void* const* d_in, const int* in_sizes, int n_in,
                              void* d_out, int out_size, void* d_ws, size_t ws_size,
                              hipStream_t stream) {
  (void)in_sizes; (void)n_in; (void)out_size; (void)ws_size;
  const float* x    = (const float*)d_in[0];
  const int*   seq  = (const int*)d_in[1];
  const float* hn   = (const float*)d_in[2];
  const float* cn   = (const float*)d_in[3];
  const float* outt = (const float*)d_in[4];
  const float* Wih  = (const float*)d_in[5];
  const float* Whh  = (const float*)d_in[6];
  const float* bih  = (const float*)d_in[7];
  const float* bhh  = (const float*)d_in[8];
  const float* Wout = (const float*)d_in[9];
  const float* bout = (const float*)d_in[10];
  float* out = (float*)d_out;
  char* ws = (char*)d_ws;

  hipLaunchKernelGGL(k_wfrag, dim3(32, 8, 40), dim3(64), 0, stream, Wih, Whh, Wout, ws);
  hipLaunchKernelGGL(k_misc, dim3(617), dim3(64), 0, stream, Wout, hn, outt, bout,
                     bih, bhh, Wih, out, ws);
  void* args[] = {(void*)&x, (void*)&seq, (void*)&cn, (void*)&bout, (void*)&out, (void*)&ws};
  hipLaunchCooperativeKernel((const void*)k_main, dim3(256), dim3(512), args, 0, stream);
}

// Round 7
// 3087.550 us; speedup vs baseline: 1.1284x; 1.0415x over previous
//
#include <hip/hip_runtime.h>
#include <stdint.h>

// AutoRegressiveLSTM: B=128, T=1024, I=128, H=1024, O=128. 4H=4096, K=I+H (+O fused)
#define Tn 1024
#define In 128

typedef __attribute__((ext_vector_type(8))) short short8;
typedef __attribute__((ext_vector_type(4))) float f32x4;
typedef unsigned long long u64;

// ---- workspace layout (bytes) ----
#define WS_WFRAG  0ull                         // 32u*8nt*40kt*64lane*16B = 10,485,760
#define WS_WOUT   (WS_WFRAG + 10485760ull)     // 8u*32kt*1024B = 262,144
#define WS_Z0     (WS_WOUT + 262144ull)        // 8m*4kt*1024B = 32,768
#define WS_HBUF   (WS_Z0 + 32768ull)           // 2buf*8m*32kt*1024B = 524,288
#define WS_BIAS   (WS_HBUF + 524288ull)        // 4096*4
#define WS_CNT    (WS_BIAS + 16384ull)         // 8m*1024t*4B flags (line-disjoint per group)
// total ~11.35 MB

__device__ __forceinline__ unsigned short f2bf(float f) {
  unsigned u = __builtin_bit_cast(unsigned, f);
  return (unsigned short)((u + 0x7FFFu + ((u >> 16) & 1u)) >> 16);  // RNE
}
__device__ __forceinline__ float fast_sig(float v) {
  float e = __builtin_amdgcn_exp2f(-1.44269504089f * v);
  return __builtin_amdgcn_rcpf(1.0f + e);
}
__device__ __forceinline__ float fast_tanh(float v) {
  float a = fabsf(v);
  float e = __builtin_amdgcn_exp2f(-2.88539008178f * a);
  float r = (1.0f - e) * __builtin_amdgcn_rcpf(1.0f + e);
  return copysignf(r, v);
}

// ---------------------------------------------------------------------------
// K1: fused weights -> bf16 fragments (used as the MFMA *A* operand now).
// Row regrouping (round-6): within wave nt, local row r=0..15 maps to
//   unit = nt*4 + (r>>2), gate = r&3   ->   n = gate*1024 + u*32 + unit
// so the gates C-tile (C[row=gate-row][col=batch]) gives each lane the 4
// gates of one unit in its 4 acc regs (C row = quad*4+reg).
//   kt 0..31  : W_comb_h[n][k] = W_hh[n][k] + sum_o W_ih[n][128+o]*W_out[o][k]
//   kt 32..35 : W_ih[n][k]           (x part)
//   kt 36..39 : W_ih[n][128+o]       (z0 correction part, t=0 only)
// ---------------------------------------------------------------------------
__global__ void k_wfrag(const float* __restrict__ Wih, const float* __restrict__ Whh,
                        const float* __restrict__ Wout, char* __restrict__ ws) {
  const int u = blockIdx.x, nt = blockIdx.y, kt = blockIdx.z;
  const int lane = threadIdx.x;
  const int col = lane & 15, quad = lane >> 4;
  const int n = (col & 3) * 1024 + u * 32 + nt * 4 + (col >> 2);   // round-6 mapping
  float v[8];
  if (kt < 32) {
    const int k = kt * 32 + quad * 8;
    #pragma unroll
    for (int e = 0; e < 8; e++) v[e] = Whh[(size_t)n * 1024 + k + e];
    const float* wo = Wih + (size_t)n * 256 + 128;
    for (int o = 0; o < 128; o++) {
      const float wv = wo[o];
      const float* wr = Wout + (size_t)o * 1024 + k;
      #pragma unroll
      for (int e = 0; e < 8; e++) v[e] = fmaf(wv, wr[e], v[e]);
    }
  } else if (kt < 36) {
    const int k = (kt - 32) * 32 + quad * 8;
    #pragma unroll
    for (int e = 0; e < 8; e++) v[e] = Wih[(size_t)n * 256 + k + e];
  } else {
    const int o = (kt - 36) * 32 + quad * 8;
    #pragma unroll
    for (int e = 0; e < 8; e++) v[e] = Wih[(size_t)n * 256 + 128 + o + e];
  }
  short8 pk;
  #pragma unroll
  for (int e = 0; e < 8; e++) pk[e] = (short)f2bf(v[e]);
  *(short8*)(ws + WS_WFRAG + ((size_t)((u * 8 + nt) * 40 + kt) * 64 + lane) * 16) = pk;
}

// ---------------------------------------------------------------------------
// K2: misc setup (woutfrag, hn->frag into hbuf[1], z0 frag, bias2, flag zero,
//     XCD-scratch zero at out[0..511])
// ---------------------------------------------------------------------------
__global__ void k_misc(const float* __restrict__ Wout, const float* __restrict__ hn,
                       const float* __restrict__ out_t, const float* __restrict__ bout,
                       const float* __restrict__ bih, const float* __restrict__ bhh,
                       const float* __restrict__ Wih, float* __restrict__ outp,
                       char* __restrict__ ws) {
  const int blk = blockIdx.x, lane = threadIdx.x;
  const int col = lane & 15, quad = lane >> 4;
  if (blk < 256) {                       // woutfrag[u][kt][lane][8] = Wout[o][j]
    const int u = blk >> 5, kt = blk & 31;
    const int o = u * 16 + col, j0 = kt * 32 + quad * 8;
    short8 pk;
    #pragma unroll
    for (int e = 0; e < 8; e++) pk[e] = (short)f2bf(Wout[(size_t)o * 1024 + j0 + e]);
    *(short8*)(ws + WS_WOUT + ((size_t)(u * 32 + kt) * 64 + lane) * 16) = pk;
  } else if (blk < 512) {                // hn -> frag layout into hbuf[1] (col=batch)
    const int t2 = blk - 256;
    const int mm = t2 >> 5, kt = t2 & 31;
    const int b = mm * 16 + col, j0 = kt * 32 + quad * 8;
    short8 pk;
    #pragma unroll
    for (int e = 0; e < 8; e++) pk[e] = (short)f2bf(hn[(size_t)b * 1024 + j0 + e]);
    *(short8*)(ws + WS_HBUF + ((size_t)((8 + mm) * 32 + kt) * 64 + lane) * 16) = pk;
  } else if (blk < 544) {                // z0 = output_t - b_out - hn@Wout^T (frag bf16)
    const int t2 = blk - 512;
    const int mm = t2 >> 2, kz = t2 & 3;
    const int b = mm * 16 + col;
    const int o0 = kz * 32 + quad * 8;
    float acc[8];
    #pragma unroll
    for (int e = 0; e < 8; e++) acc[e] = out_t[(size_t)b * 128 + o0 + e] - bout[o0 + e];
    for (int j = 0; j < 1024; j += 4) {
      const f32x4 h4 = *(const f32x4*)(hn + (size_t)b * 1024 + j);
      #pragma unroll
      for (int e = 0; e < 8; e++) {
        const f32x4 w4 = *(const f32x4*)(Wout + (size_t)(o0 + e) * 1024 + j);
        acc[e] -= h4[0] * w4[0] + h4[1] * w4[1] + h4[2] * w4[2] + h4[3] * w4[3];
      }
    }
    short8 pk;
    #pragma unroll
    for (int e = 0; e < 8; e++) pk[e] = (short)f2bf(acc[e]);
    *(short8*)(ws + WS_Z0 + ((size_t)(mm * 4 + kz) * 64 + lane) * 16) = pk;
  } else if (blk < 608) {                // bias2[n] = b_ih + b_hh + W_ihO @ b_out
    const int n = (blk - 544) * 64 + lane;
    float v = bih[n] + bhh[n];
    const float* wo = Wih + (size_t)n * 256 + 128;
    for (int o = 0; o < 128; o++) v = fmaf(wo[o], bout[o], v);
    ((float*)(ws + WS_BIAS))[n] = v;
  } else if (blk < 616) {                // zero flag counters (8192 ints)
    int* c = (int*)(ws + WS_CNT);
    const int base = ((blk - 608) * 64 + lane) * 16;
    #pragma unroll
    for (int k = 0; k < 16; k++) c[base + k] = 0;
  } else {                               // zero XCD-exchange scratch (out[0..511])
    int* c = (int*)outp;
    #pragma unroll
    for (int k = 0; k < 8; k++) c[lane * 8 + k] = 0;
  }
}

// ---------------------------------------------------------------------------
// Main persistent kernel: 256 WGs x 512 thr. R2-proven skeleton: adaptive XCD
// grouping; MALL fetch_add/spin flags; sc0 L2-local 32KB h exchange on the
// fast path; full barrier structure (incl. trailing ys barrier -- R5 showed
// removing it regresses). Round-6 delta: gates computed as
// C[gate-row][batch] = mfma(A=Wfrag, B=h-frag) with regrouped rows, so each
// lane's 4 acc regs are the 4 gates of one (unit=w*4+quad, batch=lane&15).
// Nonlinear phase is fully in-register: gates_lds + one barrier + 4
// conflict-prone LDS reads/thread eliminated. K-loop split into 4
// independent 9-deep MFMA chains (was 2x18) to cut dependent-MFMA latency.
// ---------------------------------------------------------------------------
__launch_bounds__(512, 2)
__global__ void k_main(const float* __restrict__ x, const int* __restrict__ seq,
                       const float* __restrict__ cn, const float* __restrict__ b_out,
                       float* __restrict__ out, char* __restrict__ ws) {
  __shared__ short8 a_lds[40 * 64];        // frags: 32 h + 4 x + 4 z0 (40 KB)
  __shared__ short8 htile[64];             // new h tile (16b x 32j) in frag order
  __shared__ float  ysred[8 * 16 * 20];    // ys split-K partials [q][o][b]
  __shared__ float  bo_lds[16];            // b_out slice for this WG's o-tile
  __shared__ int    seq_lds[16];

  const int tid  = threadIdx.x;
  const int lane = tid & 63;
  const int w    = tid >> 6;               // wave id 0..7 (= N-tile / unit group)
  const int wg   = blockIdx.x;

  int* cnt = (int*)(ws + WS_CNT);

  // ---- one-time placement detection + adaptive group formation (round-2) ----
  int m_, u_, fast_;
  {
    int* ids = (int*)ysred;                // 260 ints << sizeof(ysred)
    int* scr = (int*)out;
    if (tid == 0) {
      int myxcd;
      asm volatile("s_getreg_b32 %0, hwreg(HW_REG_XCC_ID)" : "=s"(myxcd));
      myxcd &= 7;
      ids[259] = myxcd;
      __hip_atomic_store(&scr[8 + wg], myxcd, __ATOMIC_RELAXED, __HIP_MEMORY_SCOPE_SYSTEM);
      __hip_atomic_fetch_add(&scr[0], 1, __ATOMIC_ACQ_REL, __HIP_MEMORY_SCOPE_SYSTEM);
      while (__hip_atomic_load(&scr[0], __ATOMIC_ACQUIRE, __HIP_MEMORY_SCOPE_SYSTEM) < 256) {}
    }
    __syncthreads();
    if (tid < 256)
      ids[tid] = __hip_atomic_load(&scr[8 + tid], __ATOMIC_RELAXED,
                                   __HIP_MEMORY_SCOPE_SYSTEM) & 7;
    __syncthreads();
    if (tid == 0) {
      const int myxcd = ids[259];
      int cx[8] = {0, 0, 0, 0, 0, 0, 0, 0};
      int rank = 0;
      for (int i = 0; i < 256; i++) {
        const int xi = ids[i];
        cx[xi]++;
        if (xi == myxcd && i < wg) rank++;
      }
      bool bal = true;
      for (int k = 0; k < 8; k++) bal = bal && (cx[k] == 32);
      ids[256] = bal ? myxcd : (wg & 7);
      ids[257] = bal ? rank : (wg >> 3);
      ids[258] = bal ? 1 : 0;
      __hip_atomic_fetch_add(&scr[1], 1, __ATOMIC_ACQ_REL, __HIP_MEMORY_SCOPE_SYSTEM);
      while (__hip_atomic_load(&scr[1], __ATOMIC_ACQUIRE, __HIP_MEMORY_SCOPE_SYSTEM) < 256) {}
    }
    __syncthreads();
    m_ = ids[256]; u_ = ids[257]; fast_ = ids[258];
    __syncthreads();                       // release overlay before ysred reuse
  }
  const int  m     = m_;
  const int  u     = u_;
  const bool fastp = (fast_ != 0);

  const char* wfrag = ws + WS_WFRAG;
  const char* woutf = ws + WS_WOUT;
  char* hbuf  = ws + WS_HBUF;
  const float* bias2 = (const float*)(ws + WS_BIAS);

  // persistent weight fragments (A operand): 40 x 16B = 160 regs
  short8 bfr[40];
  {
    const char* base = wfrag + ((size_t)(u * 8 + w) * 40 * 64) * 16 + (size_t)lane * 16;
    #pragma unroll
    for (int kt = 0; kt < 40; kt++) bfr[kt] = *(const short8*)(base + (size_t)kt * 1024);
  }
  if (tid < 16) seq_lds[tid] = seq[m * 16 + tid];
  if (tid < 16 && u < 8) bo_lds[tid] = b_out[u * 16 + tid];

  const int col16 = lane & 15;   // batch within group (C col)
  const int quad  = lane >> 4;   // unit within wave (C rows quad*4..quad*4+3)
  const int jj_my = w * 4 + quad;            // unit within WG 0..31
  float bias_g[4];
  #pragma unroll
  for (int j = 0; j < 4; j++) bias_g[j] = bias2[j * 1024 + u * 32 + jj_my];
  float c_reg = cn[(size_t)(m * 16 + col16) * 1024 + u * 32 + jj_my];
  __syncthreads();

  #pragma unroll 1
  for (int tt = 0; tt <= Tn; tt++) {
    // ---- stage x_t (masked, bf16, frag layout) -- no h dependency, overlaps spin ----
    if (tt < Tn && tid < 256) {
      const int kt4 = tid >> 6, ln = tid & 63;
      const int b = ln & 15, qd = ln >> 4;
      const int i0 = kt4 * 32 + qd * 8;
      const float* xp = x + ((size_t)(m * 16 + b) * Tn + tt) * In + i0;
      const float mk = (tt < seq_lds[b]) ? 1.0f : 0.0f;
      const f32x4 x0 = *(const f32x4*)xp;
      const f32x4 x1 = *(const f32x4*)(xp + 4);
      short8 pk;
      pk[0] = (short)f2bf(x0[0] * mk); pk[1] = (short)f2bf(x0[1] * mk);
      pk[2] = (short)f2bf(x0[2] * mk); pk[3] = (short)f2bf(x0[3] * mk);
      pk[4] = (short)f2bf(x1[0] * mk); pk[5] = (short)f2bf(x1[1] * mk);
      pk[6] = (short)f2bf(x1[2] * mk); pk[7] = (short)f2bf(x1[3] * mk);
      a_lds[(32 + kt4) * 64 + ln] = pk;
    }
    // ---- stage z0 correction frags (t=0 only) ----
    if (tt == 0 && tid < 256) {
      const int kz = tid >> 6, ln = tid & 63;
      a_lds[(36 + kz) * 64 + ln] =
          *(const short8*)(ws + WS_Z0 + ((size_t)(m * 4 + kz) * 64 + ln) * 16);
    }
    // ---- wait for all 32 producers of h_{tt-1} (round-0/2 proven MALL spin) ----
    if (tt >= 1 && tid == 0) {
      while (__hip_atomic_load(&cnt[m * 1024 + (tt - 1)], __ATOMIC_RELAXED,
                               __HIP_MEMORY_SCOPE_SYSTEM) < 32) {}
    }
    __syncthreads();
    // ---- stage h_{tt-1} (32 KB) into LDS ----
    {
      const char* srcb = hbuf + (size_t)((((tt + 1) & 1) * 8) + m) * 32768;
      if (fastp && tt >= 1) {
        // XCD-L2-local loads: data written by same-L2 sc0 stores this dispatch.
        const f32x4* sp = (const f32x4*)srcb;
        f32x4 t0, t1, t2, t3;
        asm volatile(
            "global_load_dwordx4 %0, %4, off sc0\n\t"
            "global_load_dwordx4 %1, %5, off sc0\n\t"
            "global_load_dwordx4 %2, %6, off sc0\n\t"
            "global_load_dwordx4 %3, %7, off sc0\n\t"
            "s_waitcnt vmcnt(0)"
            : "=&v"(t0), "=&v"(t1), "=&v"(t2), "=&v"(t3)
            : "v"(sp + tid), "v"(sp + 512 + tid), "v"(sp + 1024 + tid),
              "v"(sp + 1536 + tid)
            : "memory");
        f32x4* dst = (f32x4*)a_lds;
        dst[tid] = t0; dst[512 + tid] = t1; dst[1024 + tid] = t2; dst[1536 + tid] = t3;
      } else {
        const u64* src = (const u64*)srcb;
        u64 tmp[8];
        #pragma unroll
        for (int s = 0; s < 8; s++)
          tmp[s] = __hip_atomic_load(&src[s * 512 + tid], __ATOMIC_RELAXED,
                                     __HIP_MEMORY_SCOPE_SYSTEM);
        u64* dst = (u64*)a_lds;
        #pragma unroll
        for (int s = 0; s < 8; s++) dst[s * 512 + tid] = tmp[s];
      }
    }
    __syncthreads();

    // ---- gates (4 indep chains, swapped operands) + in-register NL ----
    if (tt < Tn) {
      f32x4 acc0 = {bias_g[0], bias_g[1], bias_g[2], bias_g[3]};
      f32x4 acc1 = {0.f, 0.f, 0.f, 0.f};
      f32x4 acc2 = {0.f, 0.f, 0.f, 0.f};
      f32x4 acc3 = {0.f, 0.f, 0.f, 0.f};
      #pragma unroll
      for (int kk = 0; kk < 9; kk++) {       // 4 chains x 9 deep, kt = kk*4+c
        const short8 a0 = a_lds[(kk * 4 + 0) * 64 + lane];
        const short8 a1 = a_lds[(kk * 4 + 1) * 64 + lane];
        const short8 a2 = a_lds[(kk * 4 + 2) * 64 + lane];
        const short8 a3 = a_lds[(kk * 4 + 3) * 64 + lane];
        acc0 = __builtin_amdgcn_mfma_f32_16x16x32_bf16(bfr[kk * 4 + 0], a0, acc0, 0, 0, 0);
        acc1 = __builtin_amdgcn_mfma_f32_16x16x32_bf16(bfr[kk * 4 + 1], a1, acc1, 0, 0, 0);
        acc2 = __builtin_amdgcn_mfma_f32_16x16x32_bf16(bfr[kk * 4 + 2], a2, acc2, 0, 0, 0);
        acc3 = __builtin_amdgcn_mfma_f32_16x16x32_bf16(bfr[kk * 4 + 3], a3, acc3, 0, 0, 0);
      }
      if (tt == 0) {                          // step-0 out_t correction (z kts 36..39)
        const short8 z0 = a_lds[36 * 64 + lane];
        const short8 z1 = a_lds[37 * 64 + lane];
        const short8 z2 = a_lds[38 * 64 + lane];
        const short8 z3 = a_lds[39 * 64 + lane];
        acc0 = __builtin_amdgcn_mfma_f32_16x16x32_bf16(bfr[36], z0, acc0, 0, 0, 0);
        acc1 = __builtin_amdgcn_mfma_f32_16x16x32_bf16(bfr[37], z1, acc1, 0, 0, 0);
        acc2 = __builtin_amdgcn_mfma_f32_16x16x32_bf16(bfr[38], z2, acc2, 0, 0, 0);
        acc3 = __builtin_amdgcn_mfma_f32_16x16x32_bf16(bfr[39], z3, acc3, 0, 0, 0);
      }
      {
        const float Gi = acc0[0] + acc1[0] + acc2[0] + acc3[0];
        const float Gf = acc0[1] + acc1[1] + acc2[1] + acc3[1];
        const float Gg = acc0[2] + acc1[2] + acc2[2] + acc3[2];
        const float Go = acc0[3] + acc1[3] + acc2[3] + acc3[3];
        const float ig = fast_sig(Gi), fg = fast_sig(Gf);
        const float gg = fast_tanh(Gg), og = fast_sig(Go);
        c_reg = fg * c_reg + ig * gg;
        const float h = og * fast_tanh(c_reg);
        ((short*)htile)[(col16 + 16 * (jj_my >> 3)) * 8 + (jj_my & 7)] = (short)f2bf(h);
      }
      __syncthreads();
      if (tid < 64) {                          // wave0 publishes h tile + flag (ASAP)
        const short8 v = htile[lane];
        char* dstb = hbuf + (size_t)((tt & 1) * 8 + m) * 32768 + (size_t)u * 1024 +
                     (size_t)lane * 16;
        if (fastp) {
          // XCD-L2-local store; committed at L2 before the MALL flag below.
          asm volatile("global_store_dwordx4 %0, %1, off sc0" :: "v"(dstb), "v"(v)
                       : "memory");
        } else {
          u64* dstp = (u64*)dstb;
          const u64* pv = (const u64*)&v;
          __hip_atomic_store(&dstp[0], pv[0], __ATOMIC_RELAXED, __HIP_MEMORY_SCOPE_SYSTEM);
          __hip_atomic_store(&dstp[1], pv[1], __ATOMIC_RELAXED, __HIP_MEMORY_SCOPE_SYSTEM);
        }
        asm volatile("s_waitcnt vmcnt(0)" ::: "memory");   // h committed (L2 or MALL)
        if (tid == 0)
          __hip_atomic_fetch_add(&cnt[m * 1024 + tt], 1, __ATOMIC_RELAXED,
                                 __HIP_MEMORY_SCOPE_SYSTEM);
      }
    }

    // ---- ys[tt-1] = (h_{tt-1} @ Wout^T + b_out) * mask -- off critical path ----
    if (u < 8 && tt >= 1) {
      f32x4 yacc = {0.f, 0.f, 0.f, 0.f};
      const char* wob = woutf + ((size_t)(u * 32 + w * 4) * 64 + lane) * 16;
      #pragma unroll
      for (int i = 0; i < 4; i++) {
        const short8 bf = *(const short8*)(wob + (size_t)i * 1024);
        const short8 af = a_lds[(w * 4 + i) * 64 + lane];
        yacc = __builtin_amdgcn_mfma_f32_16x16x32_bf16(af, bf, yacc, 0, 0, 0);
      }
      {
        const int o = lane & 15, bq = (lane >> 4) * 4;
        *(f32x4*)&ysred[(w * 16 + o) * 20 + bq] = yacc;
      }
      __syncthreads();
      if (tid < 256) {
        const int o = tid & 15, b = tid >> 4;
        float s = 0.f;
        #pragma unroll
        for (int q = 0; q < 8; q++) s += ysred[(q * 16 + o) * 20 + b];
        s += bo_lds[o];
        const float val = ((tt - 1) < seq_lds[b]) ? s : 0.0f;
        out[((size_t)(m * 16 + b) * Tn + (tt - 1)) * 128 + u * 16 + o] = val;
      }
      __syncthreads();                       // R2 structure (R5 removal regressed)
    }
  }
}

extern "C" void kernel_launch(void* const* d_in, const int* in_sizes, int n_in,
                              void* d_out, int out_size, void* d_ws, size_t ws_size,
                              hipStream_t stream) {
  (void)in_sizes; (void)n_in; (void)out_size; (void)ws_size;
  const float* x    = (const float*)d_in[0];
  const int*   seq  = (const int*)d_in[1];
  const float* hn   = (const float*)d_in[2];
  const float* cn   = (const float*)d_in[3];
  const float* outt = (const float*)d_in[4];
  const float* Wih  = (const float*)d_in[5];
  const float* Whh  = (const float*)d_in[6];
  const float* bih  = (const float*)d_in[7];
  const float* bhh  = (const float*)d_in[8];
  const float* Wout = (const float*)d_in[9];
  const float* bout = (const float*)d_in[10];
  float* out = (float*)d_out;
  char* ws = (char*)d_ws;

  hipLaunchKernelGGL(k_wfrag, dim3(32, 8, 40), dim3(64), 0, stream, Wih, Whh, Wout, ws);
  hipLaunchKernelGGL(k_misc, dim3(617), dim3(64), 0, stream, Wout, hn, outt, bout,
                     bih, bhh, Wih, out, ws);
  void* args[] = {(void*)&x, (void*)&seq, (void*)&cn, (void*)&bout, (void*)&out, (void*)&ws};
  hipLaunchCooperativeKernel((const void*)k_main, dim3(256), dim3(512), args, 0, stream);
}